// Round 2
// baseline (206.683 us; speedup 1.0000x reference)
//
#include <hip/hip_runtime.h>

#define NCLS 10
#define NBLK 2048          // main-kernel grid; ws holds 20 columns x NBLK partials
#define TPB  256

// ws layout (floats): column-major. ws[col*NBLK + b]
//   col in [0,10)   : per-class sqerr partial sum from block b
//   col in [10,20)  : per-class count (as float) from block b
// No zeroing needed: every block writes its 20 slots unconditionally.

__global__ __launch_bounds__(TPB) void loss_main_kernel(
    const float* __restrict__ outputs,
    const float* __restrict__ targets,
    const int*   __restrict__ mask,
    float* __restrict__ ws,
    int n4)
{
    float sum[NCLS];
#pragma unroll
    for (int c = 0; c < NCLS; ++c) sum[c] = 0.0f;
    // counts are wave-uniform (ballot+popcount) -> live in SGPRs
    int wcnt[NCLS];
#pragma unroll
    for (int c = 0; c < NCLS; ++c) wcnt[c] = 0;

    const float4* o4 = (const float4*)outputs;
    const float4* t4 = (const float4*)targets;
    const int4*   m4 = (const int4*)mask;

    const int tid = blockIdx.x * TPB + threadIdx.x;
    const int T   = NBLK * TPB;          // total threads

    for (int i = tid; i < n4; i += 2 * T) {
        // issue all 6 loads up front (2 float4-groups per stream)
        float4 o0 = o4[i];
        float4 t0 = t4[i];
        int4   m0 = m4[i];
        bool has2 = (i + T) < n4;
        int i2 = has2 ? (i + T) : i;
        float4 o1 = o4[i2];
        float4 t1 = t4[i2];
        int4   m1 = m4[i2];

        float od[8] = {o0.x, o0.y, o0.z, o0.w, o1.x, o1.y, o1.z, o1.w};
        float td[8] = {t0.x, t0.y, t0.z, t0.w, t1.x, t1.y, t1.z, t1.w};
        int   md[8] = {m0.x, m0.y, m0.z, m0.w, m1.x, m1.y, m1.z, m1.w};
        int lim = has2 ? 8 : 4;

#pragma unroll
        for (int j = 0; j < 8; ++j) {
            if (j >= lim) break;
            float d  = od[j] - td[j];
            float sq = d * d;
            // invalid pixels -> dummy class 10.0f (never matches 0..9)
            float tm = (md[j] == 1) ? td[j] : 10.0f;
#pragma unroll
            for (int c = 0; c < NCLS; ++c) {
                bool pred = (tm == (float)c);
                wcnt[c] += (int)__popcll(__ballot(pred));   // scalar pipe
                sum[c]  += pred ? sq : 0.0f;                // cmp+cndmask+add
            }
        }
    }

    // --- wave (64-lane) shuffle reduction for sums (counts already wave-wide) ---
#pragma unroll
    for (int c = 0; c < NCLS; ++c) {
#pragma unroll
        for (int off = 32; off > 0; off >>= 1)
            sum[c] += __shfl_down(sum[c], off, 64);
    }

    // --- cross-wave reduction in LDS (4 waves / block) ---
    __shared__ float lsS[4][NCLS];
    __shared__ float lsC[4][NCLS];
    int wave = threadIdx.x >> 6;
    int lane = threadIdx.x & 63;
    if (lane == 0) {
#pragma unroll
        for (int c = 0; c < NCLS; ++c) {
            lsS[wave][c] = sum[c];
            lsC[wave][c] = (float)wcnt[c];
        }
    }
    __syncthreads();

    if (threadIdx.x < 2 * NCLS) {
        int c = (threadIdx.x < NCLS) ? threadIdx.x : (threadIdx.x - NCLS);
        float v;
        if (threadIdx.x < NCLS)
            v = lsS[0][c] + lsS[1][c] + lsS[2][c] + lsS[3][c];
        else
            v = lsC[0][c] + lsC[1][c] + lsC[2][c] + lsC[3][c];
        ws[threadIdx.x * NBLK + blockIdx.x] = v;
    }
}

__global__ __launch_bounds__(TPB) void loss_final_kernel(
    const float* __restrict__ ws,
    float* __restrict__ out)
{
    // reduce 20 columns of NBLK floats each
    float acc[2 * NCLS];
#pragma unroll
    for (int k = 0; k < 2 * NCLS; ++k) acc[k] = 0.0f;

    for (int b = threadIdx.x; b < NBLK; b += TPB) {
#pragma unroll
        for (int k = 0; k < 2 * NCLS; ++k)
            acc[k] += ws[k * NBLK + b];
    }

#pragma unroll
    for (int k = 0; k < 2 * NCLS; ++k) {
#pragma unroll
        for (int off = 32; off > 0; off >>= 1)
            acc[k] += __shfl_down(acc[k], off, 64);
    }

    __shared__ float ls[4][2 * NCLS];
    __shared__ float lloss[NCLS];
    int wave = threadIdx.x >> 6;
    int lane = threadIdx.x & 63;
    if (lane == 0) {
#pragma unroll
        for (int k = 0; k < 2 * NCLS; ++k) ls[wave][k] = acc[k];
    }
    __syncthreads();

    if (threadIdx.x < NCLS) {
        int c = threadIdx.x;
        float s  = ls[0][c] + ls[1][c] + ls[2][c] + ls[3][c];
        float cn = ls[0][NCLS + c] + ls[1][NCLS + c] + ls[2][NCLS + c] + ls[3][NCLS + c];
        float le = (cn > 0.0f) ? (s / fmaxf(cn, 1.0f)) : 0.0f;
        out[1 + c]  = le;          // loss_each
        out[11 + c] = cn;          // class_n
        lloss[c] = 0.1f * le;      // WEIGHT = 0.1 per class
    }
    __syncthreads();
    if (threadIdx.x == 0) {
        float w = 0.0f;
#pragma unroll
        for (int c = 0; c < NCLS; ++c) w += lloss[c];
        out[0] = w;                // loss
    }
}

extern "C" void kernel_launch(void* const* d_in, const int* in_sizes, int n_in,
                              void* d_out, int out_size, void* d_ws, size_t ws_size,
                              hipStream_t stream)
{
    const float* outputs = (const float*)d_in[0];
    const float* targets = (const float*)d_in[1];
    const int*   mask    = (const int*)d_in[2];
    float* out = (float*)d_out;
    float* ws  = (float*)d_ws;

    int n  = in_sizes[0];
    int n4 = n / 4;   // 16,777,216 / 4 — exactly divisible

    loss_main_kernel<<<NBLK, TPB, 0, stream>>>(outputs, targets, mask, ws, n4);
    loss_final_kernel<<<1, TPB, 0, stream>>>(ws, out);
}